// Round 3
// baseline (523.350 us; speedup 1.0000x reference)
//
#include <hip/hip_runtime.h>
#include <hip/hip_bf16.h>

#define NHEAD 8
#define DKH 64
#define DMODEL 512
#define SEQ 4096
#define BATCH 2
#define MROWS (BATCH * SEQ)  // 8192

using bf16x8 = __attribute__((ext_vector_type(8))) short;
using f32x4  = __attribute__((ext_vector_type(4))) float;

__device__ __forceinline__ unsigned short f2b(float x) {
    __hip_bfloat16 h = __float2bfloat16(x);
    union { __hip_bfloat16 h; unsigned short u; } c; c.h = h; return c.u;
}
__device__ __forceinline__ float b2f(unsigned short u) {
    union { unsigned short u; __hip_bfloat16 h; } c; c.u = u; return __bfloat162float(c.h);
}

// Load 8 consecutive elements starting at element index eidx, as bf16x8.
// f32m: input buffer is float32 (convert); else it is bf16 (direct).
__device__ __forceinline__ bf16x8 ld8(const void* p, size_t eidx, bool f32m) {
    if (f32m) {
        const float* f = (const float*)p + eidx;
        float4 a = *(const float4*)f;
        float4 b = *(const float4*)(f + 4);
        bf16x8 t;
        t[0] = (short)f2b(a.x); t[1] = (short)f2b(a.y);
        t[2] = (short)f2b(a.z); t[3] = (short)f2b(a.w);
        t[4] = (short)f2b(b.x); t[5] = (short)f2b(b.y);
        t[6] = (short)f2b(b.z); t[7] = (short)f2b(b.w);
        return t;
    }
    return *(const bf16x8*)((const short*)p + eidx);
}

// ---------------------------------------------------------------------------
// Dtype probe: float32 inputs read as shorts show bf16-exponent >= 0x90
// (|x| >= 2^17) in ~44% of low-half shorts; true bf16 Wq (|w| < 0.3) shows 0.
// Round-1 NaN vs round-2 finite proved this selects the f32 branch here.
// ---------------------------------------------------------------------------
__global__ void detect_dtype(const unsigned short* __restrict__ w, int* __restrict__ flag) {
    int tid = threadIdx.x;
    int cnt = 0;
    for (int i = tid; i < 4096; i += 64) {
        unsigned short u = w[i];
        int e = (u >> 7) & 0xFF;
        if (e >= 0x90) cnt++;
    }
    for (int off = 1; off < 64; off <<= 1) cnt += __shfl_xor(cnt, off);
    if (tid == 0) flag[0] = (cnt > 64) ? 1 : 0;
}

// ---------------------------------------------------------------------------
// GEMM core: C[M,512] = A[M,512] @ W[512,512]^T + bias
// 128x128 block tile, 4 waves in 2x2, each wave 4x4 grid of 16x16 MFMA tiles.
// LDS row stride 72 bf16 (=144B: 16B-aligned, breaks 32-bank power-of-2 stride)
// f32a / f32w: A / (W,bias) buffers are fp32. f32out: store fp32 (else bf16).
// ---------------------------------------------------------------------------
template <bool HEAD_LAYOUT>
__device__ __forceinline__ void gemm_core(const void* __restrict__ A,
                                          const void* __restrict__ W,
                                          const void* __restrict__ bias,
                                          void* __restrict__ out,
                                          bool f32a, bool f32w, bool f32out) {
    __shared__ __align__(16) short lA[128 * 72];
    __shared__ __align__(16) short lB[128 * 72];

    const int bm = blockIdx.x * 128;
    const int bn = blockIdx.y * 128;
    const int tid  = threadIdx.x;
    const int lane = tid & 63;
    const int w    = tid >> 6;
    const int wr = w >> 1, wc = w & 1;   // wave position in 2x2
    const int g = lane >> 4, ln = lane & 15;

    const f32x4 zero = {0.f, 0.f, 0.f, 0.f};
    f32x4 acc[4][4];
    for (int mt = 0; mt < 4; mt++)
        for (int nt = 0; nt < 4; nt++) acc[mt][nt] = zero;

    for (int kb = 0; kb < DMODEL; kb += 64) {
        // stage 128x64 bf16 tiles of A and W (1024 vec8 each; 4 per thread)
        for (int i = 0; i < 4; i++) {
            int vv = tid + i * 256;
            int row = vv >> 3, cv = vv & 7;
            *(bf16x8*)&lA[row * 72 + cv * 8] =
                ld8(A, (size_t)(bm + row) * DMODEL + kb + cv * 8, f32a);
            *(bf16x8*)&lB[row * 72 + cv * 8] =
                ld8(W, (size_t)(bn + row) * DMODEL + kb + cv * 8, f32w);
        }
        __syncthreads();

        for (int ks = 0; ks < 2; ks++) {
            const int ko = ks * 32 + g * 8;
            bf16x8 af[4], bf[4];
            for (int mt = 0; mt < 4; mt++)
                af[mt] = *(const bf16x8*)&lA[(wr * 64 + mt * 16 + ln) * 72 + ko];
            for (int nt = 0; nt < 4; nt++)
                bf[nt] = *(const bf16x8*)&lB[(wc * 64 + nt * 16 + ln) * 72 + ko];
            for (int mt = 0; mt < 4; mt++)
                for (int nt = 0; nt < 4; nt++)
                    acc[mt][nt] = __builtin_amdgcn_mfma_f32_16x16x32_bf16(
                        af[mt], bf[nt], acc[mt][nt], 0, 0, 0);
        }
        __syncthreads();
    }

    // epilogue: bias add, store
    for (int nt = 0; nt < 4; nt++) {
        const int n = bn + wc * 64 + nt * 16 + ln;
        const float bz = f32w ? ((const float*)bias)[n]
                              : b2f((unsigned short)((const short*)bias)[n]);
        for (int mt = 0; mt < 4; mt++) {
            for (int r = 0; r < 4; r++) {
                const int m = bm + wr * 64 + mt * 16 + g * 4 + r;
                const float val = acc[mt][nt][r] + bz;
                if (HEAD_LAYOUT) {
                    // scatter to [B, H, S, DK], always bf16 (feeds attn MFMA)
                    const int bb = m >> 12, s = m & 4095;
                    const int hh = n >> 6, dk = n & 63;
                    ((short*)out)[(((size_t)(bb * NHEAD + hh)) * SEQ + s) * DKH + dk] =
                        (short)f2b(val);
                } else if (f32out) {
                    ((float*)out)[(size_t)m * DMODEL + n] = val;
                } else {
                    ((short*)out)[(size_t)m * DMODEL + n] = (short)f2b(val);
                }
            }
        }
    }
}

__global__ __launch_bounds__(256) void qkv_kernel(
    const void* __restrict__ q, const void* __restrict__ k, const void* __restrict__ v,
    const void* __restrict__ Wq, const void* __restrict__ bq,
    const void* __restrict__ Wk, const void* __restrict__ bk,
    const void* __restrict__ Wv, const void* __restrict__ bv,
    short* __restrict__ Qh, short* __restrict__ Kh, short* __restrict__ Vh,
    const int* __restrict__ flag) {
    const bool f32m = (*flag != 0);
    const void *A, *W, *B;
    short* O;
    if (blockIdx.z == 0)      { A = q; W = Wq; B = bq; O = Qh; }
    else if (blockIdx.z == 1) { A = k; W = Wk; B = bk; O = Kh; }
    else                      { A = v; W = Wv; B = bv; O = Vh; }
    gemm_core<true>(A, W, B, O, f32m, f32m, false);
}

__global__ __launch_bounds__(256) void oproj_kernel(
    const short* __restrict__ A, const void* __restrict__ W,
    const void* __restrict__ bias, void* __restrict__ out,
    const int* __restrict__ flag) {
    const bool f32m = (*flag != 0);
    // A = concat (always bf16 ws); W/bias per input dtype; OUT matches input
    // dtype (reference output dtype == reference input dtype).
    gemm_core<false>(A, W, bias, out, false, f32m, f32m);
}

// ---------------------------------------------------------------------------
// Flash attention: grid (S/64, B*H), 256 threads = 4 waves, 16 queries/wave.
// K tile [64key][64dk] row-major in LDS; V tile stored transposed [dk][key]
// so PV B-fragments are contiguous ds_read_b128. P goes C-layout -> LDS ->
// A-layout (verified m120 transform). Online softmax in fp32.
// All attn inputs are bf16 workspace intermediates (dtype-independent).
// ---------------------------------------------------------------------------
__global__ __launch_bounds__(256) void attn_kernel(
    const short* __restrict__ Qh, const short* __restrict__ Kh,
    const short* __restrict__ Vh, short* __restrict__ concat) {
    const int tid  = threadIdx.x;
    const int lane = tid & 63;
    const int w    = tid >> 6;
    const int g = lane >> 4, ln = lane & 15;
    const int bh = blockIdx.y;
    const int b = bh >> 3, h = bh & 7;
    const int qbase = blockIdx.x * 64;

    const short* Qp = Qh + (size_t)bh * SEQ * DKH;
    const short* Kp = Kh + (size_t)bh * SEQ * DKH;
    const short* Vp = Vh + (size_t)bh * SEQ * DKH;

    __shared__ __align__(16) short lK[64 * 72];
    __shared__ __align__(16) short lV[64 * 72];       // transposed [dk][key]
    __shared__ __align__(16) short lP[4][16 * 72];    // per-wave P tile

    // Q fragments (A-operand), pre-scaled by 1/sqrt(64)=0.125 (exact in bf16)
    bf16x8 qf[2];
    for (int ks = 0; ks < 2; ks++) {
        bf16x8 raw = *(const bf16x8*)&Qp[(size_t)(qbase + w * 16 + ln) * DKH + ks * 32 + g * 8];
        bf16x8 t;
        for (int j = 0; j < 8; j++)
            t[j] = (short)f2b(b2f((unsigned short)raw[j]) * 0.125f);
        qf[ks] = t;
    }

    const f32x4 zero = {0.f, 0.f, 0.f, 0.f};
    float m_r[4], l_r[4];
    f32x4 o_acc[4];
    for (int r = 0; r < 4; r++) { m_r[r] = -1e30f; l_r[r] = 0.f; }
    for (int nt = 0; nt < 4; nt++) o_acc[nt] = zero;

    for (int kb = 0; kb < SEQ; kb += 64) {
        // stage K row-major, V transposed (512 vec8 loads; 2 per thread)
        for (int i = 0; i < 2; i++) {
            int vv = tid + i * 256;
            int row = vv >> 3, cv = vv & 7;
            *(bf16x8*)&lK[row * 72 + cv * 8] =
                *(const bf16x8*)&Kp[(size_t)(kb + row) * DKH + cv * 8];
            bf16x8 raw = *(const bf16x8*)&Vp[(size_t)(kb + row) * DKH + cv * 8];
            for (int j = 0; j < 8; j++)
                lV[(cv * 8 + j) * 72 + row] = raw[j];
        }
        __syncthreads();

        // S = Q K^T  (16q x 64key per wave)
        f32x4 s[4];
        for (int nt = 0; nt < 4; nt++) {
            s[nt] = zero;
            for (int ks = 0; ks < 2; ks++) {
                bf16x8 kf = *(const bf16x8*)&lK[(nt * 16 + ln) * 72 + ks * 32 + g * 8];
                s[nt] = __builtin_amdgcn_mfma_f32_16x16x32_bf16(qf[ks], kf, s[nt], 0, 0, 0);
            }
        }

        // online softmax (rows g*4+r, cols ln+16*nt; reduce over 16 lanes)
        float rowmax[4], rowsum[4], p[4][4], alpha[4], mnew[4];
        for (int r = 0; r < 4; r++)
            rowmax[r] = fmaxf(fmaxf(s[0][r], s[1][r]), fmaxf(s[2][r], s[3][r]));
        for (int off = 1; off < 16; off <<= 1)
            for (int r = 0; r < 4; r++)
                rowmax[r] = fmaxf(rowmax[r], __shfl_xor(rowmax[r], off));
        for (int r = 0; r < 4; r++) {
            mnew[r]  = fmaxf(m_r[r], rowmax[r]);
            alpha[r] = __expf(m_r[r] - mnew[r]);
            float sum = 0.f;
            for (int nt = 0; nt < 4; nt++) {
                p[nt][r] = __expf(s[nt][r] - mnew[r]);
                sum += p[nt][r];
            }
            rowsum[r] = sum;
        }
        for (int off = 1; off < 16; off <<= 1)
            for (int r = 0; r < 4; r++)
                rowsum[r] += __shfl_xor(rowsum[r], off);
        for (int r = 0; r < 4; r++) {
            l_r[r] = l_r[r] * alpha[r] + rowsum[r];
            m_r[r] = mnew[r];
            for (int nt = 0; nt < 4; nt++) o_acc[nt][r] *= alpha[r];
        }

        // P: C-layout -> LDS (bf16)
        for (int nt = 0; nt < 4; nt++)
            for (int r = 0; r < 4; r++)
                lP[w][(g * 4 + r) * 72 + ln + 16 * nt] = (short)f2b(p[nt][r]);
        __syncthreads();

        // O += P V
        bf16x8 pf[2];
        for (int ks = 0; ks < 2; ks++)
            pf[ks] = *(const bf16x8*)&lP[w][ln * 72 + ks * 32 + g * 8];
        for (int nt = 0; nt < 4; nt++)
            for (int ks = 0; ks < 2; ks++) {
                bf16x8 vf = *(const bf16x8*)&lV[(ln + 16 * nt) * 72 + ks * 32 + g * 8];
                o_acc[nt] = __builtin_amdgcn_mfma_f32_16x16x32_bf16(pf[ks], vf, o_acc[nt], 0, 0, 0);
            }
        __syncthreads();  // protect lK/lV before next stage
    }

    // epilogue: normalize, write concat [B, S, H*DK] (bf16 ws)
    for (int nt = 0; nt < 4; nt++) {
        for (int r = 0; r < 4; r++) {
            const int qq = qbase + w * 16 + g * 4 + r;
            const int dk = ln + 16 * nt;
            const float val = o_acc[nt][r] / l_r[r];
            concat[((size_t)(b * SEQ + qq)) * DMODEL + h * DKH + dk] = (short)f2b(val);
        }
    }
}

extern "C" void kernel_launch(void* const* d_in, const int* in_sizes, int n_in,
                              void* d_out, int out_size, void* d_ws, size_t ws_size,
                              hipStream_t stream) {
    const void* q  = d_in[0];
    const void* k  = d_in[1];
    const void* v  = d_in[2];
    const void* Wq = d_in[3];
    const void* bq = d_in[4];
    const void* Wk = d_in[5];
    const void* bk = d_in[6];
    const void* Wv = d_in[7];
    const void* bv = d_in[8];
    const void* Wo = d_in[9];
    const void* bo = d_in[10];

    // ws layout: [flag:int, pad to 256B] [Qh 8MiB] [Kh 8MiB] [Vh 8MiB] [concat 8MiB]
    int*   flag   = (int*)d_ws;
    short* Qh     = (short*)((char*)d_ws + 256);
    const size_t nElemH = (size_t)BATCH * NHEAD * SEQ * DKH;  // 4,194,304
    short* Kh     = Qh + nElemH;
    short* Vh     = Kh + nElemH;
    short* concat = Vh + nElemH;

    dim3 blk(256);
    detect_dtype<<<1, 64, 0, stream>>>((const unsigned short*)Wq, flag);
    qkv_kernel<<<dim3(MROWS / 128, DMODEL / 128, 3), blk, 0, stream>>>(
        q, k, v, Wq, bq, Wk, bk, Wv, bv, Qh, Kh, Vh, flag);
    attn_kernel<<<dim3(SEQ / 64, BATCH * NHEAD), blk, 0, stream>>>(Qh, Kh, Vh, concat);
    oproj_kernel<<<dim3(MROWS / 128, DMODEL / 128), blk, 0, stream>>>(
        concat, Wo, bo, d_out, flag);
}

// Round 4
// 449.969 us; speedup vs baseline: 1.1631x; 1.1631x over previous
//
#include <hip/hip_runtime.h>
#include <hip/hip_bf16.h>

#define NHEAD 8
#define DKH 64
#define DMODEL 512
#define SEQ 4096
#define BATCH 2
#define MROWS (BATCH * SEQ)  // 8192

using bf16x8 = __attribute__((ext_vector_type(8))) short;
using bf16x4 = __attribute__((ext_vector_type(4))) short;
using f32x4  = __attribute__((ext_vector_type(4))) float;

__device__ __forceinline__ unsigned short f2b(float x) {
    __hip_bfloat16 h = __float2bfloat16(x);
    union { __hip_bfloat16 h; unsigned short u; } c; c.h = h; return c.u;
}
__device__ __forceinline__ float b2f(unsigned short u) {
    union { unsigned short u; __hip_bfloat16 h; } c; c.u = u; return __bfloat162float(c.h);
}

__device__ __forceinline__ bf16x8 ld8(const void* p, size_t eidx, bool f32m) {
    if (f32m) {
        const float* f = (const float*)p + eidx;
        float4 a = *(const float4*)f;
        float4 b = *(const float4*)(f + 4);
        bf16x8 t;
        t[0] = (short)f2b(a.x); t[1] = (short)f2b(a.y);
        t[2] = (short)f2b(a.z); t[3] = (short)f2b(a.w);
        t[4] = (short)f2b(b.x); t[5] = (short)f2b(b.y);
        t[6] = (short)f2b(b.z); t[7] = (short)f2b(b.w);
        return t;
    }
    return *(const bf16x8*)((const short*)p + eidx);
}

// Dtype probe (round-1/2 verified: selects fp32 branch on this harness).
__global__ void detect_dtype(const unsigned short* __restrict__ w, int* __restrict__ flag) {
    int tid = threadIdx.x;
    int cnt = 0;
    for (int i = tid; i < 4096; i += 64) {
        unsigned short u = w[i];
        int e = (u >> 7) & 0xFF;
        if (e >= 0x90) cnt++;
    }
    for (int off = 1; off < 64; off <<= 1) cnt += __shfl_xor(cnt, off);
    if (tid == 0) flag[0] = (cnt > 64) ? 1 : 0;
}

// ---------------------------------------------------------------------------
// GEMM core: C[m][n] = sum_k A[m,k]*W[n,k] + bias; both operands row-major-k.
// EPI 0: out[m*512+n] (f32out selects fp32/bf16)   [oproj]
// EPI 1: head scatter out[b,h,s,dk], m=token n=channel, bf16   [Q,K proj]
// EPI 2: V^T scatter out[b,h,dk,s], m=channel n=token, bias[m], bf16 [V proj]
// ---------------------------------------------------------------------------
template <int EPI>
__device__ __forceinline__ void gemm_core(const void* __restrict__ A,
                                          const void* __restrict__ W,
                                          const void* __restrict__ bias,
                                          void* __restrict__ out,
                                          bool f32a, bool f32w, bool f32out) {
    __shared__ __align__(16) short lA[128 * 72];
    __shared__ __align__(16) short lB[128 * 72];

    const int bm = blockIdx.x * 128;
    const int bn = blockIdx.y * 128;
    const int tid  = threadIdx.x;
    const int lane = tid & 63;
    const int w    = tid >> 6;
    const int wr = w >> 1, wc = w & 1;
    const int g = lane >> 4, ln = lane & 15;

    const f32x4 zero = {0.f, 0.f, 0.f, 0.f};
    f32x4 acc[4][4];
    for (int mt = 0; mt < 4; mt++)
        for (int nt = 0; nt < 4; nt++) acc[mt][nt] = zero;

    for (int kb = 0; kb < DMODEL; kb += 64) {
        for (int i = 0; i < 4; i++) {
            int vv = tid + i * 256;
            int row = vv >> 3, cv = vv & 7;
            *(bf16x8*)&lA[row * 72 + cv * 8] =
                ld8(A, (size_t)(bm + row) * DMODEL + kb + cv * 8, f32a);
            *(bf16x8*)&lB[row * 72 + cv * 8] =
                ld8(W, (size_t)(bn + row) * DMODEL + kb + cv * 8, f32w);
        }
        __syncthreads();

        for (int ks = 0; ks < 2; ks++) {
            const int ko = ks * 32 + g * 8;
            bf16x8 af[4], bf[4];
            for (int mt = 0; mt < 4; mt++)
                af[mt] = *(const bf16x8*)&lA[(wr * 64 + mt * 16 + ln) * 72 + ko];
            for (int nt = 0; nt < 4; nt++)
                bf[nt] = *(const bf16x8*)&lB[(wc * 64 + nt * 16 + ln) * 72 + ko];
            for (int mt = 0; mt < 4; mt++)
                for (int nt = 0; nt < 4; nt++)
                    acc[mt][nt] = __builtin_amdgcn_mfma_f32_16x16x32_bf16(
                        af[mt], bf[nt], acc[mt][nt], 0, 0, 0);
        }
        __syncthreads();
    }

    if (EPI == 2) {
        // rows = output channel (bias index), cols = token; write V^T
        for (int mt = 0; mt < 4; mt++) {
            for (int r = 0; r < 4; r++) {
                const int m = bm + wr * 64 + mt * 16 + g * 4 + r;  // channel
                const float bz = f32w ? ((const float*)bias)[m]
                                      : b2f((unsigned short)((const short*)bias)[m]);
                const int hh = m >> 6, dk = m & 63;
                for (int nt = 0; nt < 4; nt++) {
                    const int n = bn + wc * 64 + nt * 16 + ln;     // token
                    const int bb = n >> 12, s = n & 4095;
                    ((short*)out)[(((size_t)(bb * NHEAD + hh)) * DKH + dk) * SEQ + s] =
                        (short)f2b(acc[mt][nt][r] + bz);
                }
            }
        }
    } else {
        for (int nt = 0; nt < 4; nt++) {
            const int n = bn + wc * 64 + nt * 16 + ln;
            const float bz = f32w ? ((const float*)bias)[n]
                                  : b2f((unsigned short)((const short*)bias)[n]);
            for (int mt = 0; mt < 4; mt++) {
                for (int r = 0; r < 4; r++) {
                    const int m = bm + wr * 64 + mt * 16 + g * 4 + r;
                    const float val = acc[mt][nt][r] + bz;
                    if (EPI == 1) {
                        const int bb = m >> 12, s = m & 4095;
                        const int hh = n >> 6, dk = n & 63;
                        ((short*)out)[(((size_t)(bb * NHEAD + hh)) * SEQ + s) * DKH + dk] =
                            (short)f2b(val);
                    } else if (f32out) {
                        ((float*)out)[(size_t)m * DMODEL + n] = val;
                    } else {
                        ((short*)out)[(size_t)m * DMODEL + n] = (short)f2b(val);
                    }
                }
            }
        }
    }
}

__global__ __launch_bounds__(256) void qk_kernel(
    const void* __restrict__ q, const void* __restrict__ k,
    const void* __restrict__ Wq, const void* __restrict__ bq,
    const void* __restrict__ Wk, const void* __restrict__ bk,
    short* __restrict__ Qh, short* __restrict__ Kh,
    const int* __restrict__ flag) {
    const bool f32m = (*flag != 0);
    const void *A, *W, *B;
    short* O;
    if (blockIdx.z == 0) { A = q; W = Wq; B = bq; O = Qh; }
    else                 { A = k; W = Wk; B = bk; O = Kh; }
    gemm_core<1>(A, W, B, O, f32m, f32m, false);
}

// V projection, operand-swapped: D = Wv * v^T = Vh^T, written as [b,h,dk,s]
__global__ __launch_bounds__(256) void vproj_kernel(
    const void* __restrict__ Wv, const void* __restrict__ v,
    const void* __restrict__ bv, short* __restrict__ Vt,
    const int* __restrict__ flag) {
    const bool f32m = (*flag != 0);
    gemm_core<2>(Wv, v, bv, Vt, f32m, f32m, false);
}

__global__ __launch_bounds__(256) void oproj_kernel(
    const short* __restrict__ A, const void* __restrict__ W,
    const void* __restrict__ bias, void* __restrict__ out,
    const int* __restrict__ flag) {
    const bool f32m = (*flag != 0);
    gemm_core<0>(A, W, bias, out, false, f32m, f32m);
}

// ---------------------------------------------------------------------------
// Flash attention v2: grid (S/64, B*H), 4 waves, 16 q/wave, BK=128 keys/tile.
// S^T = K*Q^T (operand swap): C-layout gives each thread one softmax row
// (q = ln) -> 2-shuffle reductions, scalar m/l state, and P repacks in
// REGISTERS into the PV A-operand (key slot j <-> g*4+(j&3)+16*(j>>2)).
// V^T comes pre-transposed from vproj; PV B-fragments = 2x ds_read_b64.
// 2 barriers per 128 keys; no scalar LDS writes anywhere.
// ---------------------------------------------------------------------------
__global__ __launch_bounds__(256) void attn_kernel(
    const short* __restrict__ Qh, const short* __restrict__ Kh,
    const short* __restrict__ Vt, short* __restrict__ concat) {
    const int tid  = threadIdx.x;
    const int lane = tid & 63;
    const int w    = tid >> 6;
    const int g = lane >> 4, ln = lane & 15;
    const int bh = blockIdx.y;
    const int b = bh >> 3, h = bh & 7;
    const int qbase = blockIdx.x * 64;

    const short* Qp = Qh + (size_t)bh * SEQ * DKH;
    const short* Kp = Kh + (size_t)bh * SEQ * DKH;
    const short* Vp = Vt + (size_t)bh * DKH * SEQ;   // [dk][s]

    __shared__ __align__(16) short lK[128 * 72];
    __shared__ __align__(16) short lV[64 * 136];     // [dk][key], stride 136

    // Q fragments (B-operand), row q = qbase + w*16 + ln, scaled 1/8 (exact)
    bf16x8 qf[2];
    for (int ks = 0; ks < 2; ks++) {
        bf16x8 raw = *(const bf16x8*)&Qp[(size_t)(qbase + w * 16 + ln) * DKH + ks * 32 + g * 8];
        bf16x8 t;
        for (int j = 0; j < 8; j++)
            t[j] = (short)f2b(b2f((unsigned short)raw[j]) * 0.125f);
        qf[ks] = t;
    }

    const f32x4 zero = {0.f, 0.f, 0.f, 0.f};
    float m_r = -1e30f, l_r = 0.f;                   // state for q = ln
    f32x4 o_acc[4];
    for (int nt = 0; nt < 4; nt++) o_acc[nt] = zero;

    for (int kb = 0; kb < SEQ; kb += 128) {
        // stage K [128key][64dk] and V^T [64dk][128key], all b128
        for (int i = 0; i < 4; i++) {
            int vv = tid + i * 256;
            {
                int row = vv >> 3, cv = vv & 7;
                *(bf16x8*)&lK[row * 72 + cv * 8] =
                    *(const bf16x8*)&Kp[(size_t)(kb + row) * DKH + cv * 8];
            }
            {
                int dk = vv >> 4, kc = vv & 15;
                *(bf16x8*)&lV[dk * 136 + kc * 8] =
                    *(const bf16x8*)&Vp[(size_t)dk * SEQ + kb + kc * 8];
            }
        }
        __syncthreads();

        // S^T tile: thread holds S^T[key = nt*16+g*4+r][q=ln], nt 0..7
        f32x4 st[8];
        for (int nt = 0; nt < 8; nt++) {
            bf16x8 kf0 = *(const bf16x8*)&lK[(nt * 16 + ln) * 72 + g * 8];
            bf16x8 kf1 = *(const bf16x8*)&lK[(nt * 16 + ln) * 72 + 32 + g * 8];
            f32x4 a = zero;
            a = __builtin_amdgcn_mfma_f32_16x16x32_bf16(kf0, qf[0], a, 0, 0, 0);
            a = __builtin_amdgcn_mfma_f32_16x16x32_bf16(kf1, qf[1], a, 0, 0, 0);
            st[nt] = a;
        }

        // online softmax over 128 keys (row q=ln spread across 4 g-lanes)
        float rowmax = st[0][0];
        for (int nt = 0; nt < 8; nt++)
            for (int r = 0; r < 4; r++) rowmax = fmaxf(rowmax, st[nt][r]);
        rowmax = fmaxf(rowmax, __shfl_xor(rowmax, 16));
        rowmax = fmaxf(rowmax, __shfl_xor(rowmax, 32));
        const float mnew  = fmaxf(m_r, rowmax);
        const float alpha = __expf(m_r - mnew);
        float sum = 0.f;
        for (int nt = 0; nt < 8; nt++)
            for (int r = 0; r < 4; r++) {
                float pv = __expf(st[nt][r] - mnew);
                st[nt][r] = pv;
                sum += pv;
            }
        sum += __shfl_xor(sum, 16);
        sum += __shfl_xor(sum, 32);
        l_r = l_r * alpha + sum;
        m_r = mnew;

        // rescale O (C-layout rows q = g*4+r need alpha from lane g*4+r)
        float ar[4];
        for (int r = 0; r < 4; r++) ar[r] = __shfl(alpha, g * 4 + r);
        for (int nt = 0; nt < 4; nt++)
            for (int r = 0; r < 4; r++) o_acc[nt][r] *= ar[r];

        // pack P into A-fragments (registers only)
        bf16x8 pf[4];
        for (int hh = 0; hh < 4; hh++) {
            bf16x8 t;
            for (int j = 0; j < 8; j++)
                t[j] = (short)f2b(st[hh * 2 + (j >> 2)][j & 3]);
            pf[hh] = t;
        }

        // O += P V  (B-fragments: keys h*32+g*4+{0..3} and +16..19)
        for (int hh = 0; hh < 4; hh++) {
            for (int nt = 0; nt < 4; nt++) {
                const int base = (nt * 16 + ln) * 136 + hh * 32 + g * 4;
                bf16x4 v0 = *(const bf16x4*)&lV[base];
                bf16x4 v1 = *(const bf16x4*)&lV[base + 16];
                bf16x8 vf;
                for (int j = 0; j < 4; j++) { vf[j] = v0[j]; vf[4 + j] = v1[j]; }
                o_acc[nt] = __builtin_amdgcn_mfma_f32_16x16x32_bf16(pf[hh], vf, o_acc[nt], 0, 0, 0);
            }
        }
        __syncthreads();  // protect lK/lV before next stage
    }

    // epilogue: O rows q=g*4+r need l from lane g*4+r
    float lf[4];
    for (int r = 0; r < 4; r++) lf[r] = __shfl(l_r, g * 4 + r);
    for (int nt = 0; nt < 4; nt++) {
        for (int r = 0; r < 4; r++) {
            const int qq = qbase + w * 16 + g * 4 + r;
            const int dk = nt * 16 + ln;
            concat[((size_t)(b * SEQ + qq)) * DMODEL + h * DKH + dk] =
                (short)f2b(o_acc[nt][r] / lf[r]);
        }
    }
}

extern "C" void kernel_launch(void* const* d_in, const int* in_sizes, int n_in,
                              void* d_out, int out_size, void* d_ws, size_t ws_size,
                              hipStream_t stream) {
    const void* q  = d_in[0];
    const void* k  = d_in[1];
    const void* v  = d_in[2];
    const void* Wq = d_in[3];
    const void* bq = d_in[4];
    const void* Wk = d_in[5];
    const void* bk = d_in[6];
    const void* Wv = d_in[7];
    const void* bv = d_in[8];
    const void* Wo = d_in[9];
    const void* bo = d_in[10];

    int*   flag   = (int*)d_ws;
    short* Qh     = (short*)((char*)d_ws + 256);
    const size_t nElemH = (size_t)BATCH * NHEAD * SEQ * DKH;  // 4,194,304
    short* Kh     = Qh + nElemH;
    short* Vt     = Kh + nElemH;   // [b,h,dk,s]
    short* concat = Vt + nElemH;

    dim3 blk(256);
    detect_dtype<<<1, 64, 0, stream>>>((const unsigned short*)Wq, flag);
    qk_kernel<<<dim3(MROWS / 128, DMODEL / 128, 2), blk, 0, stream>>>(
        q, k, Wq, bq, Wk, bk, Qh, Kh, flag);
    vproj_kernel<<<dim3(DMODEL / 128, MROWS / 128), blk, 0, stream>>>(
        Wv, v, bv, Vt, flag);
    attn_kernel<<<dim3(SEQ / 64, BATCH * NHEAD), blk, 0, stream>>>(Qh, Kh, Vt, concat);
    oproj_kernel<<<dim3(MROWS / 128, DMODEL / 128), blk, 0, stream>>>(
        concat, Wo, bo, d_out, flag);
}

// Round 5
// 314.500 us; speedup vs baseline: 1.6641x; 1.4307x over previous
//
#include <hip/hip_runtime.h>
#include <hip/hip_bf16.h>

#define NHEAD 8
#define DKH 64
#define DMODEL 512
#define SEQ 4096
#define BATCH 2
#define MROWS (BATCH * SEQ)  // 8192

using bf16x8 = __attribute__((ext_vector_type(8))) short;
using f32x4  = __attribute__((ext_vector_type(4))) float;
using f32x16 = __attribute__((ext_vector_type(16))) float;

__device__ __forceinline__ unsigned short f2b(float x) {
    __hip_bfloat16 h = __float2bfloat16(x);
    union { __hip_bfloat16 h; unsigned short u; } c; c.h = h; return c.u;
}
__device__ __forceinline__ float b2f(unsigned short u) {
    union { unsigned short u; __hip_bfloat16 h; } c; c.u = u; return __bfloat162float(c.h);
}

__device__ __forceinline__ bf16x8 ld8(const void* p, size_t eidx, bool f32m) {
    if (f32m) {
        const float* f = (const float*)p + eidx;
        float4 a = *(const float4*)f;
        float4 b = *(const float4*)(f + 4);
        bf16x8 t;
        t[0] = (short)f2b(a.x); t[1] = (short)f2b(a.y);
        t[2] = (short)f2b(a.z); t[3] = (short)f2b(a.w);
        t[4] = (short)f2b(b.x); t[5] = (short)f2b(b.y);
        t[6] = (short)f2b(b.z); t[7] = (short)f2b(b.w);
        return t;
    }
    return *(const bf16x8*)((const short*)p + eidx);
}

// Dtype probe (rounds 1-4 verified: selects fp32 branch on this harness).
__global__ void detect_dtype(const unsigned short* __restrict__ w, int* __restrict__ flag) {
    int tid = threadIdx.x;
    int cnt = 0;
    for (int i = tid; i < 4096; i += 64) {
        unsigned short u = w[i];
        int e = (u >> 7) & 0xFF;
        if (e >= 0x90) cnt++;
    }
    for (int off = 1; off < 64; off <<= 1) cnt += __shfl_xor(cnt, off);
    if (tid == 0) flag[0] = (cnt > 64) ? 1 : 0;
}

// One-time f32->bf16 conversion (or copy) of the 7 big inputs into ws.
__global__ __launch_bounds__(256) void cvt_kernel(
    const void* s0, const void* s1, const void* s2, const void* s3,
    const void* s4, const void* s5, const void* s6,
    short* d0, short* d1, short* d2, short* d3,
    short* d4, short* d5, short* d6, const int* __restrict__ flag) {
    const void* src; short* dst; int n;
    switch (blockIdx.y) {
        case 0: src = s0; dst = d0; n = MROWS * DMODEL; break;
        case 1: src = s1; dst = d1; n = MROWS * DMODEL; break;
        case 2: src = s2; dst = d2; n = MROWS * DMODEL; break;
        case 3: src = s3; dst = d3; n = DMODEL * DMODEL; break;
        case 4: src = s4; dst = d4; n = DMODEL * DMODEL; break;
        case 5: src = s5; dst = d5; n = DMODEL * DMODEL; break;
        default: src = s6; dst = d6; n = DMODEL * DMODEL; break;
    }
    int idx = (blockIdx.x * 256 + threadIdx.x) * 8;
    if (idx >= n) return;
    *(bf16x8*)&dst[idx] = ld8(src, idx, *flag != 0);
}

// ---------------------------------------------------------------------------
// GEMM core: C[m][n] = sum_k A[m,k]*W[n,k] + bias.
// EPI 0: out[m*512+n] (f32out picks fp32/bf16)        [oproj]
// EPI 1: head scatter [b,h,s,dk], bf16                [Q,K proj]
// EPI 2: permuted V^T scatter [b,h,dk,perm(s)], bf16  [V proj]
//        perm makes attn's PV B-operand a pure in-register repack.
// ---------------------------------------------------------------------------
template <int EPI>
__device__ __forceinline__ void gemm_core(const void* __restrict__ A,
                                          const void* __restrict__ W,
                                          const void* __restrict__ bias,
                                          void* __restrict__ out,
                                          bool f32a, bool f32w, bool f32b,
                                          bool f32out) {
    __shared__ __align__(16) short lA[128 * 72];
    __shared__ __align__(16) short lB[128 * 72];

    const int bm = blockIdx.x * 128;
    const int bn = blockIdx.y * 128;
    const int tid  = threadIdx.x;
    const int lane = tid & 63;
    const int w    = tid >> 6;
    const int wr = w >> 1, wc = w & 1;
    const int g = lane >> 4, ln = lane & 15;

    const f32x4 zero = {0.f, 0.f, 0.f, 0.f};
    f32x4 acc[4][4];
    for (int mt = 0; mt < 4; mt++)
        for (int nt = 0; nt < 4; nt++) acc[mt][nt] = zero;

    for (int kb = 0; kb < DMODEL; kb += 64) {
        for (int i = 0; i < 4; i++) {
            int vv = tid + i * 256;
            int row = vv >> 3, cv = vv & 7;
            *(bf16x8*)&lA[row * 72 + cv * 8] =
                ld8(A, (size_t)(bm + row) * DMODEL + kb + cv * 8, f32a);
            *(bf16x8*)&lB[row * 72 + cv * 8] =
                ld8(W, (size_t)(bn + row) * DMODEL + kb + cv * 8, f32w);
        }
        __syncthreads();

        for (int ks = 0; ks < 2; ks++) {
            const int ko = ks * 32 + g * 8;
            bf16x8 af[4], bf[4];
            for (int mt = 0; mt < 4; mt++)
                af[mt] = *(const bf16x8*)&lA[(wr * 64 + mt * 16 + ln) * 72 + ko];
            for (int nt = 0; nt < 4; nt++)
                bf[nt] = *(const bf16x8*)&lB[(wc * 64 + nt * 16 + ln) * 72 + ko];
            for (int mt = 0; mt < 4; mt++)
                for (int nt = 0; nt < 4; nt++)
                    acc[mt][nt] = __builtin_amdgcn_mfma_f32_16x16x32_bf16(
                        af[mt], bf[nt], acc[mt][nt], 0, 0, 0);
        }
        __syncthreads();
    }

    if (EPI == 2) {
        // rows = output channel (bias index), cols = token; write permuted V^T
        for (int mt = 0; mt < 4; mt++) {
            for (int r = 0; r < 4; r++) {
                const int m = bm + wr * 64 + mt * 16 + g * 4 + r;  // channel
                const float bz = f32b ? ((const float*)bias)[m]
                                      : b2f((unsigned short)((const short*)bias)[m]);
                const int hh = m >> 6, dk = m & 63;
                for (int nt = 0; nt < 4; nt++) {
                    const int n = bn + wc * 64 + nt * 16 + ln;     // token
                    const int bb = n >> 12, s = n & 4095;
                    // key permutation within 128-blocks (see attn PV derivation)
                    const int sl = s & 127, sh = s & ~127;
                    const int kt = sl >> 5, kk = sl & 31;
                    const int t = kk >> 3, hb = (kk >> 2) & 1, lo = kk & 3;
                    const int kappa = kt * 32 + (t >> 1) * 16 + hb * 8 + (t & 1) * 4 + lo;
                    ((short*)out)[(((size_t)(bb * NHEAD + hh)) * DKH + dk) * SEQ + sh + kappa] =
                        (short)f2b(acc[mt][nt][r] + bz);
                }
            }
        }
    } else {
        for (int nt = 0; nt < 4; nt++) {
            const int n = bn + wc * 64 + nt * 16 + ln;
            const float bz = f32b ? ((const float*)bias)[n]
                                  : b2f((unsigned short)((const short*)bias)[n]);
            for (int mt = 0; mt < 4; mt++) {
                for (int r = 0; r < 4; r++) {
                    const int m = bm + wr * 64 + mt * 16 + g * 4 + r;
                    const float val = acc[mt][nt][r] + bz;
                    if (EPI == 1) {
                        const int bb = m >> 12, s = m & 4095;
                        const int hh = n >> 6, dk = n & 63;
                        ((short*)out)[(((size_t)(bb * NHEAD + hh)) * SEQ + s) * DKH + dk] =
                            (short)f2b(val);
                    } else if (f32out) {
                        ((float*)out)[(size_t)m * DMODEL + n] = val;
                    } else {
                        ((short*)out)[(size_t)m * DMODEL + n] = (short)f2b(val);
                    }
                }
            }
        }
    }
}

__global__ __launch_bounds__(256) void qk_kernel(
    const void* __restrict__ q, const void* __restrict__ k,
    const void* __restrict__ Wq, const void* __restrict__ bq,
    const void* __restrict__ Wk, const void* __restrict__ bk,
    short* __restrict__ Qh, short* __restrict__ Kh,
    const int* __restrict__ flag, int conv) {
    const bool fin = conv ? false : (*flag != 0);
    const bool fb  = (*flag != 0);
    const void *A, *W, *B;
    short* O;
    if (blockIdx.z == 0) { A = q; W = Wq; B = bq; O = Qh; }
    else                 { A = k; W = Wk; B = bk; O = Kh; }
    gemm_core<1>(A, W, B, O, fin, fin, fb, false);
}

__global__ __launch_bounds__(256) void vproj_kernel(
    const void* __restrict__ Wv, const void* __restrict__ v,
    const void* __restrict__ bv, short* __restrict__ Vt,
    const int* __restrict__ flag, int conv) {
    const bool fin = conv ? false : (*flag != 0);
    const bool fb  = (*flag != 0);
    gemm_core<2>(Wv, v, bv, Vt, fin, fin, fb, false);
}

__global__ __launch_bounds__(256) void oproj_kernel(
    const short* __restrict__ A, const void* __restrict__ W,
    const void* __restrict__ bias, void* __restrict__ out,
    const int* __restrict__ flag, int conv) {
    const bool fin = conv ? false : (*flag != 0);
    const bool fb  = (*flag != 0);
    gemm_core<0>(A, W, bias, out, false, fin, fb, fb);
}

// ---------------------------------------------------------------------------
// Flash attention v3: 32x32x16 MFMA. Grid (S/128, B*H), 4 waves, 32 q/wave.
// S^T = K*Q^T: C-layout col = lane&31 = q -> each thread owns ONE softmax row
// (in-thread reduce + single xor-32 shuffle; scalar m/l/alpha).
// O^T = V^T * P: V^T comes key-PERMUTED from vproj so P's B-fragments are a
// pure in-register repack of the S^T C-layout: pf[j] = st[ks2>>1][8*(ks2&1)
// + 4*(j>>2) + (j&3)]. 2 barriers / 128 keys; no P or Q LDS at all.
// A/B frag layout (32x32x16): row = lane&31, k = (lane>>5)*8 + j.
// C/D layout (verified m74/m101): col = lane&31, row=(r&3)+8*(r>>2)+4*(lane>>5).
// ---------------------------------------------------------------------------
__global__ __launch_bounds__(256) void attn_kernel(
    const short* __restrict__ Qh, const short* __restrict__ Kh,
    const short* __restrict__ Vt, short* __restrict__ concat) {
    const int tid  = threadIdx.x;
    const int lane = tid & 63;
    const int w    = tid >> 6;
    const int c  = lane & 31;
    const int h5 = lane >> 5;
    const int bh = blockIdx.y;
    const int b = bh >> 3, h = bh & 7;
    const int qbase = blockIdx.x * 128;
    const int qw = qbase + w * 32;

    const short* Qp = Qh + (size_t)bh * SEQ * DKH;
    const short* Kp = Kh + (size_t)bh * SEQ * DKH;
    const short* Vp = Vt + (size_t)bh * DKH * SEQ;   // [dk][perm(s)]

    __shared__ __align__(16) short lK[128 * 72];
    __shared__ __align__(16) short lV[64 * 136];

    // Q B-fragments: B[k=dk][n=q]: lane reads Q[qw+c][ks*16 + h5*8 + 0..7]
    bf16x8 qf[4];
    for (int ks = 0; ks < 4; ks++) {
        bf16x8 raw = *(const bf16x8*)&Qp[(size_t)(qw + c) * DKH + ks * 16 + h5 * 8];
        bf16x8 t;
        for (int j = 0; j < 8; j++)
            t[j] = (short)f2b(b2f((unsigned short)raw[j]) * 0.125f);
        qf[ks] = t;
    }

    const float L2E = 1.44269504f;
    float m2_r = -3e38f, l_r = 0.f;   // log2-domain max; state for q = qw+c
    f32x16 o_acc[2];
    for (int dt = 0; dt < 2; dt++)
        for (int r = 0; r < 16; r++) o_acc[dt][r] = 0.f;

    for (int kb = 0; kb < SEQ; kb += 128) {
        // stage K [128key][64dk] stride 72, V^T [64dk][128kappa] stride 136
        for (int i = 0; i < 4; i++) {
            int vv = tid + i * 256;
            {
                int row = vv >> 3, cv = vv & 7;
                *(bf16x8*)&lK[row * 72 + cv * 8] =
                    *(const bf16x8*)&Kp[(size_t)(kb + row) * DKH + cv * 8];
            }
            {
                int dk = vv >> 4, kc = vv & 15;
                *(bf16x8*)&lV[dk * 136 + kc * 8] =
                    *(const bf16x8*)&Vp[(size_t)dk * SEQ + kb + kc * 8];
            }
        }
        __syncthreads();

        // S^T: st[kt] holds keys kt*32 + (r&3)+8*(r>>2)+4*h5, q = qw+c
        f32x16 st[4];
        for (int kt = 0; kt < 4; kt++)
            for (int r = 0; r < 16; r++) st[kt][r] = 0.f;
        for (int ks = 0; ks < 4; ks++)
            for (int kt = 0; kt < 4; kt++) {
                bf16x8 kf = *(const bf16x8*)&lK[(kt * 32 + c) * 72 + ks * 16 + h5 * 8];
                st[kt] = __builtin_amdgcn_mfma_f32_32x32x16_bf16(kf, qf[ks], st[kt], 0, 0, 0);
            }

        // online softmax: whole 128-key row split between (c,h5) and (c,h5^1)
        float mx = st[0][0];
        for (int kt = 0; kt < 4; kt++)
            for (int r = 0; r < 16; r++) mx = fmaxf(mx, st[kt][r]);
        mx = fmaxf(mx, __shfl_xor(mx, 32));
        const float m2new = fmaxf(m2_r, mx * L2E);
        const float alpha = exp2f(m2_r - m2new);
        float sum = 0.f;
        for (int kt = 0; kt < 4; kt++)
            for (int r = 0; r < 16; r++) {
                float p = exp2f(fmaf(st[kt][r], L2E, -m2new));
                st[kt][r] = p;
                sum += p;
            }
        sum += __shfl_xor(sum, 32);
        l_r = l_r * alpha + sum;
        m2_r = m2new;
        for (int dt = 0; dt < 2; dt++)
            for (int r = 0; r < 16; r++) o_acc[dt][r] *= alpha;

        // O^T += V^T * P  (P B-fragments: pure in-register repack)
        for (int ks2 = 0; ks2 < 8; ks2++) {
            const int kt = ks2 >> 1, ob = 8 * (ks2 & 1);
            bf16x8 pf;
            for (int j = 0; j < 8; j++)
                pf[j] = (short)f2b(st[kt][ob + 4 * (j >> 2) + (j & 3)]);
            for (int dt = 0; dt < 2; dt++) {
                bf16x8 vf = *(const bf16x8*)&lV[(dt * 32 + c) * 136 + ks2 * 16 + h5 * 8];
                o_acc[dt] = __builtin_amdgcn_mfma_f32_32x32x16_bf16(vf, pf, o_acc[dt], 0, 0, 0);
            }
        }
        __syncthreads();
    }

    // epilogue: O^T[dk][q], q = qw+c; write concat [B,S,H*DK] bf16
    const float inv = 1.0f / l_r;
    const int qq = qw + c;
    short* crow = concat + ((size_t)(b * SEQ + qq)) * DMODEL + h * DKH;
    for (int dt = 0; dt < 2; dt++)
        for (int r = 0; r < 16; r++) {
            const int dk = dt * 32 + (r & 3) + 8 * (r >> 2) + 4 * h5;
            crow[dk] = (short)f2b(o_acc[dt][r] * inv);
        }
}

extern "C" void kernel_launch(void* const* d_in, const int* in_sizes, int n_in,
                              void* d_out, int out_size, void* d_ws, size_t ws_size,
                              hipStream_t stream) {
    const void* q  = d_in[0];
    const void* k  = d_in[1];
    const void* v  = d_in[2];
    const void* Wq = d_in[3];
    const void* bq = d_in[4];
    const void* Wk = d_in[5];
    const void* bk = d_in[6];
    const void* Wv = d_in[7];
    const void* bv = d_in[8];
    const void* Wo = d_in[9];
    const void* bo = d_in[10];

    const size_t nElemH = (size_t)BATCH * NHEAD * SEQ * DKH;  // 4,194,304
    const size_t nElemW = (size_t)DMODEL * DMODEL;            // 262,144

    int*   flag   = (int*)d_ws;
    short* Qh     = (short*)((char*)d_ws + 256);
    short* Kh     = Qh + nElemH;
    short* Vt     = Kh + nElemH;          // [b,h,dk,perm(s)]
    short* concat = Vt + nElemH;
    short* qb     = concat + nElemH;      // converted inputs (tier-full)
    short* kb_    = qb + nElemH;
    short* vb     = kb_ + nElemH;
    short* Wqb    = vb + nElemH;
    short* Wkb    = Wqb + nElemW;
    short* Wvb    = Wkb + nElemW;
    short* Wob    = Wvb + nElemW;

    const size_t needed = 256 + (4 + 3) * nElemH * 2 + 4 * nElemW * 2;
    const int conv = (ws_size >= needed) ? 1 : 0;

    dim3 blk(256);
    detect_dtype<<<1, 64, 0, stream>>>((const unsigned short*)Wq, flag);

    const void *qx = q, *kx = k, *vx = v, *Wqx = Wq, *Wkx = Wk, *Wvx = Wv, *Wox = Wo;
    if (conv) {
        cvt_kernel<<<dim3(2048, 7), blk, 0, stream>>>(
            q, k, v, Wq, Wk, Wv, Wo, qb, kb_, vb, Wqb, Wkb, Wvb, Wob, flag);
        qx = qb; kx = kb_; vx = vb; Wqx = Wqb; Wkx = Wkb; Wvx = Wvb; Wox = Wob;
    }

    qk_kernel<<<dim3(MROWS / 128, DMODEL / 128, 2), blk, 0, stream>>>(
        qx, kx, Wqx, bq, Wkx, bk, Qh, Kh, flag, conv);
    vproj_kernel<<<dim3(DMODEL / 128, MROWS / 128), blk, 0, stream>>>(
        Wvx, vx, bv, Vt, flag, conv);
    attn_kernel<<<dim3(SEQ / 128, BATCH * NHEAD), blk, 0, stream>>>(Qh, Kh, Vt, concat);
    oproj_kernel<<<dim3(MROWS / 128, DMODEL / 128), blk, 0, stream>>>(
        concat, Wox, bo, d_out, flag, conv);
}